// Round 7
// baseline (4275.463 us; speedup 1.0000x reference)
//
#include <hip/hip_runtime.h>
#include <stdint.h>

#define SLEN    512
#define IDIM    256
#define HDIM    512
#define NROW    256          // 2 sequences x 128 batch rows
#define HPH     520          // Abh row stride in halfs (512+8): 1040B -> dword%32==4
#define NSTEP   512
#define NGRP    16           // batch groups (16 rows each)
#define GWG     16           // WGs (column groups) per batch group

typedef __attribute__((ext_vector_type(8))) _Float16 half8;
typedef __attribute__((ext_vector_type(4))) float   f32x4;
typedef __attribute__((ext_vector_type(4))) int     i32x4;

#define AS1 __attribute__((address_space(1)))
#define AS3 __attribute__((address_space(3)))

__device__ __forceinline__ float sigm(float x)   { return 1.0f / (1.0f + __expf(-x)); }
__device__ __forceinline__ float tanh_f(float x) { return 2.0f / (1.0f + __expf(-2.0f * x)) - 1.0f; }

__device__ __forceinline__ half8 cvt8(float4 a, float4 b) {
    half8 v;
    v[0] = (_Float16)a.x; v[1] = (_Float16)a.y; v[2] = (_Float16)a.z; v[3] = (_Float16)a.w;
    v[4] = (_Float16)b.x; v[5] = (_Float16)b.y; v[6] = (_Float16)b.z; v[7] = (_Float16)b.w;
    return v;
}

union hu { _Float16 h; unsigned short u; };

// Round-7: single-barrier step, x fully in registers.
//  - x B-frags load straight from global into regs (per-lane row l16): the x
//    LDS path and barrier A1 are deleted. h-region LDS reuse stays ordered by
//    the flag protocol (a wave's flag posts only after its h-GEMM LDS reads
//    completed, program order; h staging is gated on all 64 flags).
//  - x-GEMM is reg-only -> issues BEFORE the flag check, covering the
//    pre-issued flag load (pf, issued at prev tail; one pure vmcnt(0) drains
//    it; stale value -> proven poll fallback).
//  - x(t+1) raw loads keep R6's slot (issue after h-drain, fly over A2, drain
//    at tail vmcnt(0)); cvt to f16 at tail, off the serial chain.
//  - tail: h-store -> vmcnt(0) -> flag -> pf-issue -> cvt. No ds ops at tail.
// Sync primitives: vmcnt(0)-only drains, raw s_barrier, sc0+sc1 everywhere —
// all R6-proven. No counted vmcnt, no new cache-scope assumptions.
__global__ __launch_bounds__(256, 1)
void lstm_persistent(const float* __restrict__ x0, const float* __restrict__ x1,
                     const float* __restrict__ wih, const float* __restrict__ whh,
                     const float* __restrict__ bih, const float* __restrict__ bhh,
                     _Float16* __restrict__ hb, int* __restrict__ flg,
                     float* __restrict__ out) {
    __shared__ __align__(16) _Float16 Abh[16 * HPH];

    const int tid  = threadIdx.x;
    const int lane = tid & 63;
    const int w    = tid >> 6;       // wave 0..3
    const int quad = lane >> 4;
    const int l16  = lane & 15;
    const int igrp = blockIdx.x & 15;    // batch group (16 rows)
    const int jcg  = blockIdx.x >> 4;    // column group (32 H-cols)

    // ---- W A-frags: global fp32 -> f16 regs/AGPRs, once ----
    const int q0  = l16 & 3, ccl = l16 >> 2;
    const int colb = jcg * 32 + w * 8 + ccl * 2;
    const int gc0 = q0 * HDIM + colb;
    const int gc1 = gc0 + 1;
    half8 wf0[24], wf1[24];
#pragma unroll
    for (int kk = 0; kk < 24; ++kk) {
        int k0 = kk * 32 + quad * 8;
        const float* sA = (k0 < IDIM) ? wih + (size_t)gc0 * IDIM + k0
                                      : whh + (size_t)gc0 * HDIM + (k0 - IDIM);
        const float* sB = (k0 < IDIM) ? wih + (size_t)gc1 * IDIM + k0
                                      : whh + (size_t)gc1 * HDIM + (k0 - IDIM);
        wf0[kk] = cvt8(*(const float4*)sA, *(const float4*)(sA + 4));
        wf1[kk] = cvt8(*(const float4*)sB, *(const float4*)(sB + 4));
    }

    float bias0[4], bias1[4];
#pragma unroll
    for (int q = 0; q < 4; ++q) {
        int g0 = q * HDIM + jcg * 32 + w * 8 + quad * 2;
        bias0[q] = bih[g0] + bhh[g0];
        bias1[q] = bih[g0 + 1] + bhh[g0 + 1];
    }

    const float* xp  = (igrp < 8) ? x0 : x1;
    const int   brow = (igrp & 7) * 16;
    const int   grow = igrp * 16 + l16;     // my batch row (global)
    const int   cc0  = jcg * 32 + w * 8 + quad * 2;   // my H-cols (cc0, cc0+1)

    // per-lane x source: row (brow+l16), col segment quad*8 (+kk*32 per chunk)
    const float* xrow = xp + (size_t)(brow + l16) * SLEN * IDIM + quad * 8;

    const int* fpoll = flg + igrp * 64 + lane;          // 64 wave-flags of my group
    int*       fmine = flg + igrp * 64 + jcg * 4 + w;   // my wave's flag

    float c0 = 0.f, c1 = 0.f;
    int gaveup = 0;
    int pf = 0;     // pre-issued flag value for next step's check

    // ---- prologue: x(0) B-frags into regs (plain loads; latency irrelevant) ----
    half8 xf[8];
#pragma unroll
    for (int kk = 0; kk < 8; ++kk) {
        const float* p = xrow + (size_t)kk * 32;
        xf[kk] = cvt8(*(const float4*)p, *(const float4*)(p + 4));
    }

#pragma unroll 1
    for (int t = 0; t < NSTEP; ++t) {
        // ---- x-part GEMM (K=256, reg-only): covers pf flight / producer skew ----
        f32x4 acc0 = {bias0[0], bias0[1], bias0[2], bias0[3]};
        f32x4 acc1 = {bias1[0], bias1[1], bias1[2], bias1[3]};
#pragma unroll
        for (int kk = 0; kk < 8; ++kk) {
            acc0 = __builtin_amdgcn_mfma_f32_16x16x32_f16(wf0[kk], xf[kk], acc0, 0, 0, 0);
            acc1 = __builtin_amdgcn_mfma_f32_16x16x32_f16(wf1[kk], xf[kk], acc1, 0, 0, 0);
        }
        __builtin_amdgcn_sched_barrier(0);

        // ---- flag check: pf drained by one pure vmcnt(0); stale -> poll ----
        if (t > 0 && !gaveup) {
            asm volatile("s_waitcnt vmcnt(0)" ::: "memory");
            __builtin_amdgcn_sched_barrier(0);
            if (!__all(pf >= t)) {
                int it = 0;
                while (true) {
                    int f;
                    asm volatile("global_load_dword %0, %1, off sc0 sc1\n\t"
                                 "s_waitcnt vmcnt(0)"
                                 : "=&v"(f) : "v"(fpoll) : "memory");
                    if (__all(f >= t)) break;
                    __builtin_amdgcn_s_sleep(1);
                    if (++it > (1 << 20)) { gaveup = 1; break; }
                }
            }
            __builtin_amdgcn_fence(__ATOMIC_ACQUIRE, "workgroup");
        }

        // ---- h_{t-1} staging: 4x global_load_lds (aux=17), pure full drain ----
        {
            const _Float16* hsrc = hb + (size_t)((t + 1) & 1) * (NROW * HDIM)
                                      + (size_t)(igrp * 16) * HDIM;
#pragma unroll
            for (int p = 0; p < 4; ++p) {
                const int r = p * 4 + w;
                const _Float16* g = hsrc + (size_t)r * HDIM + lane * 8;
                __builtin_amdgcn_global_load_lds(
                    (const AS1 void*)g, (AS3 void*)&Abh[r * HPH],
                    16, 0, 17);
            }
            asm volatile("s_waitcnt vmcnt(0)" ::: "memory");
            __builtin_amdgcn_sched_barrier(0);
        }

        // ---- x(t+1) raw prefetch (16x dwordx4, pinned): flies across A2,
        //      drained by the tail vmcnt(0), cvt'd at tail off-chain ----
        i32x4 xr0_, xr1_, xr2_, xr3_, xr4_, xr5_, xr6_, xr7_;
        i32x4 xr8_, xr9_, xrA_, xrB_, xrC_, xrD_, xrE_, xrF_;
        if (t < NSTEP - 1) {
            const float* xb = xrow + (size_t)(t + 1) * IDIM;
            asm volatile(
                "global_load_dwordx4 %0, %8, off\n\t"
                "global_load_dwordx4 %1, %8, off offset:16\n\t"
                "global_load_dwordx4 %2, %8, off offset:128\n\t"
                "global_load_dwordx4 %3, %8, off offset:144\n\t"
                "global_load_dwordx4 %4, %8, off offset:256\n\t"
                "global_load_dwordx4 %5, %8, off offset:272\n\t"
                "global_load_dwordx4 %6, %8, off offset:384\n\t"
                "global_load_dwordx4 %7, %8, off offset:400"
                : "=&v"(xr0_), "=&v"(xr1_), "=&v"(xr2_), "=&v"(xr3_),
                  "=&v"(xr4_), "=&v"(xr5_), "=&v"(xr6_), "=&v"(xr7_)
                : "v"(xb) : "memory");
            asm volatile(
                "global_load_dwordx4 %0, %8, off offset:512\n\t"
                "global_load_dwordx4 %1, %8, off offset:528\n\t"
                "global_load_dwordx4 %2, %8, off offset:640\n\t"
                "global_load_dwordx4 %3, %8, off offset:656\n\t"
                "global_load_dwordx4 %4, %8, off offset:768\n\t"
                "global_load_dwordx4 %5, %8, off offset:784\n\t"
                "global_load_dwordx4 %6, %8, off offset:896\n\t"
                "global_load_dwordx4 %7, %8, off offset:912"
                : "=&v"(xr8_), "=&v"(xr9_), "=&v"(xrA_), "=&v"(xrB_),
                  "=&v"(xrC_), "=&v"(xrD_), "=&v"(xrE_), "=&v"(xrF_)
                : "v"(xb) : "memory");
        }
        __builtin_amdgcn_sched_barrier(0);
        __builtin_amdgcn_s_barrier();   // A2 (the only barrier): h staged

        // ---- h-part GEMM (K=512) ----
        const _Float16* abh = &Abh[l16 * HPH + quad * 8];
#pragma unroll
        for (int kk = 0; kk < 16; ++kk) {
            half8 bf = *(const half8*)(abh + kk * 32);
            acc0 = __builtin_amdgcn_mfma_f32_16x16x32_f16(wf0[8 + kk], bf, acc0, 0, 0, 0);
            acc1 = __builtin_amdgcn_mfma_f32_16x16x32_f16(wf1[8 + kk], bf, acc1, 0, 0, 0);
        }

        // ---- cell update (regs 0..3 = i,f,g,o), fp32 ----
        float i0 = sigm(acc0[0]), f0 = sigm(acc0[1]), g0 = tanh_f(acc0[2]), o0g = sigm(acc0[3]);
        c0 = f0 * c0 + i0 * g0;
        float h0 = o0g * tanh_f(c0);
        float i1 = sigm(acc1[0]), f1 = sigm(acc1[1]), g1 = tanh_f(acc1[2]), o1g = sigm(acc1[3]);
        c1 = f1 * c1 + i1 * g1;
        float h1 = o1g * tanh_f(c1);

        if (t < NSTEP - 1) {
            // h store -> drain (ack overlaps x residual) -> flag -> pf -> cvt
            _Float16* hd = hb + (size_t)(t & 1) * (NROW * HDIM) + (size_t)grow * HDIM;
            hu u0; u0.h = (_Float16)h0;
            hu u1; u1.h = (_Float16)h1;
            unsigned int hp = (unsigned int)u0.u | ((unsigned int)u1.u << 16);
            asm volatile("global_store_dword %0, %1, off sc0 sc1"
                         :: "v"((int*)(hd + cc0)), "v"(hp) : "memory");
            __builtin_amdgcn_sched_barrier(0);
            asm volatile("s_waitcnt vmcnt(0)" ::: "memory");
            __builtin_amdgcn_sched_barrier(0);
            if (lane == 0) {
                int fv = t + 1;
                asm volatile("global_store_dword %0, %1, off sc0 sc1"
                             :: "v"(fmine), "v"(fv) : "memory");
            }
            // pre-issue next step's flag read (zero-init: premature copy -> poll)
            asm volatile("v_mov_b32 %0, 0\n\t"
                         "global_load_dword %0, %1, off sc0 sc1"
                         : "=&v"(pf) : "v"(fpoll) : "memory");
            // cvt x(t+1) raw -> f16 B-frags (off the serial chain)
            xf[0] = cvt8(*(float4*)&xr0_, *(float4*)&xr1_);
            xf[1] = cvt8(*(float4*)&xr2_, *(float4*)&xr3_);
            xf[2] = cvt8(*(float4*)&xr4_, *(float4*)&xr5_);
            xf[3] = cvt8(*(float4*)&xr6_, *(float4*)&xr7_);
            xf[4] = cvt8(*(float4*)&xr8_, *(float4*)&xr9_);
            xf[5] = cvt8(*(float4*)&xrA_, *(float4*)&xrB_);
            xf[6] = cvt8(*(float4*)&xrC_, *(float4*)&xrD_);
            xf[7] = cvt8(*(float4*)&xrE_, *(float4*)&xrF_);
        } else {
            float2 ov; ov.x = h0; ov.y = h1;
            *(float2*)(out + (size_t)grow * HDIM + cc0) = ov;
        }
    }
}

extern "C" void kernel_launch(void* const* d_in, const int* in_sizes, int n_in,
                              void* d_out, int out_size, void* d_ws, size_t ws_size,
                              hipStream_t stream) {
    const float* x0  = (const float*)d_in[0];   // [128,512,256] fp32
    const float* x1  = (const float*)d_in[1];
    const float* wih = (const float*)d_in[2];   // [2048,256]
    const float* whh = (const float*)d_in[3];   // [2048,512]
    const float* bih = (const float*)d_in[4];   // [2048]
    const float* bhh = (const float*)d_in[5];   // [2048]

    // ws: h ping-pong (2 x 256 KB f16) + per-(group,wave) flags (16 x 64 ints)
    _Float16* hb = (_Float16*)d_ws;
    int* flg = (int*)((char*)d_ws + (size_t)2 * NROW * HDIM * sizeof(_Float16));
    size_t zbytes = (size_t)2 * NROW * HDIM * sizeof(_Float16)
                  + (size_t)NGRP * 64 * sizeof(int);
    hipMemsetAsync(d_ws, 0, zbytes, stream);   // zero h_{-1} + flags

    lstm_persistent<<<dim3(256), dim3(256), 0, stream>>>(
        x0, x1, wih, whh, bih, bhh, hb, flg, (float*)d_out);
}

// Round 8
// 1748.873 us; speedup vs baseline: 2.4447x; 2.4447x over previous
//
#include <hip/hip_runtime.h>
#include <stdint.h>

#define SLEN    512
#define IDIM    256
#define HDIM    512
#define NROW    256          // 2 sequences x 128 batch rows
#define HPH     520          // h LDS row stride in halfs (512+8): 2-way banks
#define XPF     260          // x LDS row stride in floats (256+4): 2-way banks
#define NSTEP   512
#define NGRP    16           // batch groups (16 rows each)
#define GWG     16           // WGs (column groups) per batch group

typedef __attribute__((ext_vector_type(8))) _Float16 half8;
typedef __attribute__((ext_vector_type(4))) float   f32x4;

#define AS1 __attribute__((address_space(1)))
#define AS3 __attribute__((address_space(3)))

__device__ __forceinline__ float sigm(float x)   { return 1.0f / (1.0f + __expf(-x)); }
__device__ __forceinline__ float tanh_f(float x) { return 2.0f / (1.0f + __expf(-2.0f * x)) - 1.0f; }

__device__ __forceinline__ half8 cvt8(float4 a, float4 b) {
    half8 v;
    v[0] = (_Float16)a.x; v[1] = (_Float16)a.y; v[2] = (_Float16)a.z; v[3] = (_Float16)a.w;
    v[4] = (_Float16)b.x; v[5] = (_Float16)b.y; v[6] = (_Float16)b.z; v[7] = (_Float16)b.w;
    return v;
}

union hu { _Float16 h; unsigned short u; };

// Round-8: single-barrier step, zero ds_writes, poll hidden under reg-only x-GEMM.
// R6's chain = 3 LLC RTs (~1600cy each: poll, h-load, store-ack) + compute.
//  - x double-buffered in LDS via global_load_lds (f32 rows, 1024B = 1 op,
//    coalesced — R7's per-lane direct loads were the regression). Issued
//    mid-step with the h-DMA, drained by the same vmcnt(0)+A2. At the TAIL
//    (after flag, off-chain) each wave ds_reads x(t+1) -> regs (xf).
//  - x-GEMM is register-only at step top -> barrier A1 deleted (one barrier).
//    The poll's FIRST iteration is hoisted before x-GEMM: issue flag load,
//    16 MFMAs, vmcnt(0), check. Covers ~400cy of the poll RT. Stale -> R6's
//    poll fallback (no cross-step register lifetime, unlike R7's pf).
//  - h-GEMM split into 4 accumulator chains (halves MFMA latency chain).
// Cross-wave LDS safety (no A1) — every reuse is separated by the A2 barrier:
//  * Hb[t&1] written by h-DMA(t) (after check(t), i.e. after A2(t-1)); last
//    read by h-GEMM(t-2) which precedes tail(t-2) -> top(t-1) -> A2(t-1). OK.
//  * Xb[(t+1)&1] written by x-DMA (mid-step t, before A2(t)); read at
//    tail(t) (after A2(t)). Previous read of that buffer was tail(t-2),
//    which precedes A2(t-1) -> mid-step t. OK.
// Flag protocol (store -> vmcnt(0) ack -> flag), sc0 sc1 ops, full-drain-only
// waits: unchanged from R6. No counted vmcnt anywhere.
__global__ __launch_bounds__(256, 1)
void lstm_persistent(const float* __restrict__ x0, const float* __restrict__ x1,
                     const float* __restrict__ wih, const float* __restrict__ whh,
                     const float* __restrict__ bih, const float* __restrict__ bhh,
                     _Float16* __restrict__ hb, int* __restrict__ flg,
                     float* __restrict__ out) {
    __shared__ __align__(16) _Float16 Hb[2][16 * HPH];
    __shared__ __align__(16) float    Xb[2][16 * XPF];

    const int tid  = threadIdx.x;
    const int lane = tid & 63;
    const int w    = tid >> 6;       // wave 0..3
    const int quad = lane >> 4;
    const int l16  = lane & 15;
    const int igrp = blockIdx.x & 15;    // batch group (16 rows)
    const int jcg  = blockIdx.x >> 4;    // column group (32 H-cols)

    // ---- W A-frags: global fp32 -> f16 regs/AGPRs, once ----
    const int q0  = l16 & 3, ccl = l16 >> 2;
    const int colb = jcg * 32 + w * 8 + ccl * 2;
    const int gc0 = q0 * HDIM + colb;
    const int gc1 = gc0 + 1;
    half8 wf0[24], wf1[24];
#pragma unroll
    for (int kk = 0; kk < 24; ++kk) {
        int k0 = kk * 32 + quad * 8;
        const float* sA = (k0 < IDIM) ? wih + (size_t)gc0 * IDIM + k0
                                      : whh + (size_t)gc0 * HDIM + (k0 - IDIM);
        const float* sB = (k0 < IDIM) ? wih + (size_t)gc1 * IDIM + k0
                                      : whh + (size_t)gc1 * HDIM + (k0 - IDIM);
        wf0[kk] = cvt8(*(const float4*)sA, *(const float4*)(sA + 4));
        wf1[kk] = cvt8(*(const float4*)sB, *(const float4*)(sB + 4));
    }

    float bias0[4], bias1[4];
#pragma unroll
    for (int q = 0; q < 4; ++q) {
        int g0 = q * HDIM + jcg * 32 + w * 8 + quad * 2;
        bias0[q] = bih[g0] + bhh[g0];
        bias1[q] = bih[g0 + 1] + bhh[g0 + 1];
    }

    const float* xp  = (igrp < 8) ? x0 : x1;
    const int   brow = (igrp & 7) * 16;
    const int   grow = igrp * 16 + l16;     // my batch row (global)
    const int   cc0  = jcg * 32 + w * 8 + quad * 2;   // my H-cols (cc0, cc0+1)

    const int* fpoll = flg + igrp * 64 + lane;          // 64 wave-flags of my group
    int*       fmine = flg + igrp * 64 + jcg * 4 + w;   // my wave's flag

    float c0 = 0.f, c1 = 0.f;
    int gaveup = 0;

    // ---- prologue: x(0) DMA -> Xb[0]; ds_read -> xf regs ----
    half8 xf[8];
    {
#pragma unroll
        for (int p = 0; p < 4; ++p) {
            const int r = p * 4 + w;
            const float* g = xp + (size_t)(brow + r) * SLEN * IDIM + lane * 4;
            __builtin_amdgcn_global_load_lds(
                (const AS1 void*)g, (AS3 void*)&Xb[0][r * XPF], 16, 0, 0);
        }
        asm volatile("s_waitcnt vmcnt(0)" ::: "memory");
        __builtin_amdgcn_sched_barrier(0);
        __builtin_amdgcn_s_barrier();
        const float* xb = &Xb[0][l16 * XPF + quad * 8];
#pragma unroll
        for (int kk = 0; kk < 8; ++kk)
            xf[kk] = cvt8(*(const float4*)(xb + kk * 32),
                          *(const float4*)(xb + kk * 32 + 4));
    }

#pragma unroll 1
    for (int t = 0; t < NSTEP; ++t) {
        // ---- hoisted first-poll issue (covered by the reg-only x-GEMM) ----
        int f0 = 0;
        if (t > 0) {
            asm volatile("global_load_dword %0, %1, off sc0 sc1"
                         : "=&v"(f0) : "v"(fpoll) : "memory");
            __builtin_amdgcn_sched_barrier(0);
        }

        // ---- x-part GEMM (K=256, reg-only; no barrier needed) ----
        f32x4 acc0 = {bias0[0], bias0[1], bias0[2], bias0[3]};
        f32x4 acc1 = {bias1[0], bias1[1], bias1[2], bias1[3]};
#pragma unroll
        for (int kk = 0; kk < 8; ++kk) {
            acc0 = __builtin_amdgcn_mfma_f32_16x16x32_f16(wf0[kk], xf[kk], acc0, 0, 0, 0);
            acc1 = __builtin_amdgcn_mfma_f32_16x16x32_f16(wf1[kk], xf[kk], acc1, 0, 0, 0);
        }
        __builtin_amdgcn_sched_barrier(0);

        // ---- check (drain = first-poll + prev flag-store residual); fallback poll ----
        if (t > 0 && !gaveup) {
            asm volatile("s_waitcnt vmcnt(0)" ::: "memory");
            __builtin_amdgcn_sched_barrier(0);
            if (!__all(f0 >= t)) {
                int it = 0;
                while (true) {
                    int f;
                    asm volatile("global_load_dword %0, %1, off sc0 sc1\n\t"
                                 "s_waitcnt vmcnt(0)"
                                 : "=&v"(f) : "v"(fpoll) : "memory");
                    if (__all(f >= t)) break;
                    __builtin_amdgcn_s_sleep(1);
                    if (++it > (1 << 20)) { gaveup = 1; break; }
                }
            }
            __builtin_amdgcn_fence(__ATOMIC_ACQUIRE, "workgroup");
        }

        // ---- h_{t-1} DMA -> Hb[t&1]; x(t+1) DMA -> Xb[(t+1)&1]; one drain ----
        {
            const _Float16* hsrc = hb + (size_t)((t + 1) & 1) * (NROW * HDIM)
                                      + (size_t)(igrp * 16) * HDIM;
#pragma unroll
            for (int p = 0; p < 4; ++p) {
                const int r = p * 4 + w;
                __builtin_amdgcn_global_load_lds(
                    (const AS1 void*)(hsrc + (size_t)r * HDIM + lane * 8),
                    (AS3 void*)&Hb[t & 1][r * HPH], 16, 0, 17);
            }
            if (t < NSTEP - 1) {
#pragma unroll
                for (int p = 0; p < 4; ++p) {
                    const int r = p * 4 + w;
                    const float* g = xp + (size_t)(brow + r) * SLEN * IDIM
                                        + (size_t)(t + 1) * IDIM + lane * 4;
                    __builtin_amdgcn_global_load_lds(
                        (const AS1 void*)g, (AS3 void*)&Xb[(t + 1) & 1][r * XPF],
                        16, 0, 0);
                }
            }
        }
        asm volatile("s_waitcnt vmcnt(0)" ::: "memory");
        __builtin_amdgcn_sched_barrier(0);
        __builtin_amdgcn_s_barrier();   // A2 (the only barrier): h + x staged

        // ---- h-part GEMM (K=512), 4 accumulator chains ----
        {
            const _Float16* abh = &Hb[t & 1][l16 * HPH + quad * 8];
            f32x4 b0 = {0.f, 0.f, 0.f, 0.f}, b1 = {0.f, 0.f, 0.f, 0.f};
#pragma unroll
            for (int kk = 0; kk < 16; kk += 2) {
                half8 bfa = *(const half8*)(abh + kk * 32);
                half8 bfb = *(const half8*)(abh + (kk + 1) * 32);
                acc0 = __builtin_amdgcn_mfma_f32_16x16x32_f16(wf0[8 + kk], bfa, acc0, 0, 0, 0);
                b0   = __builtin_amdgcn_mfma_f32_16x16x32_f16(wf0[9 + kk], bfb, b0, 0, 0, 0);
                acc1 = __builtin_amdgcn_mfma_f32_16x16x32_f16(wf1[8 + kk], bfa, acc1, 0, 0, 0);
                b1   = __builtin_amdgcn_mfma_f32_16x16x32_f16(wf1[9 + kk], bfb, b1, 0, 0, 0);
            }
            acc0 += b0;
            acc1 += b1;
        }

        // ---- cell update (regs 0..3 = i,f,g,o), fp32 ----
        float i0 = sigm(acc0[0]), f0g = sigm(acc0[1]), g0 = tanh_f(acc0[2]), o0g = sigm(acc0[3]);
        c0 = f0g * c0 + i0 * g0;
        float h0 = o0g * tanh_f(c0);
        float i1 = sigm(acc1[0]), f1g = sigm(acc1[1]), g1 = tanh_f(acc1[2]), o1g = sigm(acc1[3]);
        c1 = f1g * c1 + i1 * g1;
        float h1 = o1g * tanh_f(c1);

        if (t < NSTEP - 1) {
            // h store -> ack (pure: queue empty) -> flag -> x(t+1) reload (off-chain)
            _Float16* hd = hb + (size_t)(t & 1) * (NROW * HDIM) + (size_t)grow * HDIM;
            hu u0; u0.h = (_Float16)h0;
            hu u1; u1.h = (_Float16)h1;
            unsigned int hp = (unsigned int)u0.u | ((unsigned int)u1.u << 16);
            asm volatile("global_store_dword %0, %1, off sc0 sc1"
                         :: "v"((int*)(hd + cc0)), "v"(hp) : "memory");
            __builtin_amdgcn_sched_barrier(0);
            asm volatile("s_waitcnt vmcnt(0)" ::: "memory");
            __builtin_amdgcn_sched_barrier(0);
            if (lane == 0) {
                int fv = t + 1;
                asm volatile("global_store_dword %0, %1, off sc0 sc1"
                             :: "v"(fmine), "v"(fv) : "memory");
            }
            // xf reload for step t+1 (ds_read + cvt, after flag: off the chain)
            const float* xb = &Xb[(t + 1) & 1][l16 * XPF + quad * 8];
#pragma unroll
            for (int kk = 0; kk < 8; ++kk)
                xf[kk] = cvt8(*(const float4*)(xb + kk * 32),
                              *(const float4*)(xb + kk * 32 + 4));
        } else {
            float2 ov; ov.x = h0; ov.y = h1;
            *(float2*)(out + (size_t)grow * HDIM + cc0) = ov;
        }
    }
}

extern "C" void kernel_launch(void* const* d_in, const int* in_sizes, int n_in,
                              void* d_out, int out_size, void* d_ws, size_t ws_size,
                              hipStream_t stream) {
    const float* x0  = (const float*)d_in[0];   // [128,512,256] fp32
    const float* x1  = (const float*)d_in[1];
    const float* wih = (const float*)d_in[2];   // [2048,256]
    const float* whh = (const float*)d_in[3];   // [2048,512]
    const float* bih = (const float*)d_in[4];   // [2048]
    const float* bhh = (const float*)d_in[5];   // [2048]

    // ws: h ping-pong (2 x 256 KB f16) + per-(group,wave) flags (16 x 64 ints)
    _Float16* hb = (_Float16*)d_ws;
    int* flg = (int*)((char*)d_ws + (size_t)2 * NROW * HDIM * sizeof(_Float16));
    size_t zbytes = (size_t)2 * NROW * HDIM * sizeof(_Float16)
                  + (size_t)NGRP * 64 * sizeof(int);
    hipMemsetAsync(d_ws, 0, zbytes, stream);   // zero h_{-1} + flags

    lstm_persistent<<<dim3(256), dim3(256), 0, stream>>>(
        x0, x1, wih, whh, bih, bhh, hb, flg, (float*)d_out);
}